// Round 19
// baseline (170.601 us; speedup 1.0000x reference)
//
#include <hip/hip_runtime.h>
#include <hip/hip_bf16.h>

// ---------------------------------------------------------------------------
// Part_Graph: deformable-conv message passing over a 6-node part graph.
// B=2, H=W=96, IN=256, HID=10, P=6, E=12, K=9 taps.  ALL I/O is float32.
// dcn: offset-conv AND sampling tap-matvec via bf16 MFMA (16x16x32).
// BN1/BN2 stats: per-wave NON-ATOMIC partials + tiny tree-reduce kernel.
// mgq: 512-thread c-split (half A: c0-127 + gate, half B: c128-255, LDS join).
// ---------------------------------------------------------------------------

#define NE 12
#define NPART 6
#define BB 2
#define HH 96
#define WW 96
#define HWD (HH*WW)          // 9216
#define CIN2 20              // 2*HID concat channels
#define NHID 10
#define NIN 256

// LDS tile geometry: 16x16 output tile, +-2 halo -> 20x20 box.
#define BOX 20
#define BCOL 21              // pix = rr*BCOL + cc
#define NPIX (BOX*BCOL)      // 420
#define GHALF (NPIX*8)       // ushorts per 8-channel group = 3360
#define SROW 40              // s-tile row stride (ushorts): 80 B, 16B-aligned

typedef __attribute__((ext_vector_type(8))) short s16x8;
typedef __attribute__((ext_vector_type(4))) float f32x4;

__device__ __forceinline__ float sigf(float x) { return 1.f / (1.f + __expf(-x)); }
__device__ __forceinline__ float bfbits2f(unsigned int u) {
    return __uint_as_float(u << 16);
}
__device__ __forceinline__ unsigned short f2bfbits(float v) {
    __hip_bfloat16 h = __float2bfloat16(v);
    return *reinterpret_cast<unsigned short*>(&h);
}
// Intra-wave LDS fence (guide rule #18).
__device__ __forceinline__ void wave_lds_fence() {
    asm volatile("s_waitcnt lgkmcnt(0)" ::: "memory");
    __builtin_amdgcn_sched_barrier(0);
}

// ---------------------------------------------------------------------------
// Weight prep (bf16 MFMA B-fragments + fp32 bias + fp32 upd).
// ---------------------------------------------------------------------------
__global__ __launch_bounds__(256)
void xpose_weights(const float* __restrict__ off1_w, const float* __restrict__ off1_b,
                   const float* __restrict__ dcn1_w,
                   const float* __restrict__ off2_w, const float* __restrict__ off2_b,
                   const float* __restrict__ dcn2_w,
                   const float* __restrict__ upd_w,
                   unsigned short* __restrict__ bf1, float* __restrict__ o1b,
                   unsigned short* __restrict__ ws1,
                   unsigned short* __restrict__ bf2, float* __restrict__ o2b,
                   unsigned short* __restrict__ ws2,
                   float* __restrict__ uwt)
{
    int idx = blockIdx.x * 256 + threadIdx.x;
    if (idx < 110592) {                      // bf1 [e][t][nt][lane][i]
        int e = idx / 9216, r = idx % 9216;
        int t = r / 1024, r2 = r % 1024;
        int nt = r2 / 512, r3 = r2 % 512;
        int lane = r3 / 8, i = r3 % 8;
        int k = (lane >> 4)*8 + i;
        int col = nt*16 + (lane & 15);
        float v = (k < CIN2 && col < 27) ? off1_w[((e*27 + col)*CIN2 + k)*9 + t] : 0.f;
        bf1[idx] = f2bfbits(v);
        return;
    }
    idx -= 110592;
    if (idx < 324) { o1b[idx] = off1_b[idx]; return; }
    idx -= 324;
    if (idx < 110592) {                      // ws1 [e][t][nt][lane][i]  (COUT=20)
        int e = idx / 9216, r = idx % 9216;
        int t = r / 1024, r2 = r % 1024;
        int nt = r2 / 512, r3 = r2 % 512;
        int lane = r3 / 8, i = r3 % 8;
        int c = (lane >> 4)*8 + i;
        int o = nt*16 + (lane & 15);
        float v = (c < CIN2 && o < CIN2) ? dcn1_w[((e*20 + o)*CIN2 + c)*9 + t] : 0.f;
        ws1[idx] = f2bfbits(v);
        return;
    }
    idx -= 110592;
    if (idx < 110592) {                      // bf2
        int e = idx / 9216, r = idx % 9216;
        int t = r / 1024, r2 = r % 1024;
        int nt = r2 / 512, r3 = r2 % 512;
        int lane = r3 / 8, i = r3 % 8;
        int k = (lane >> 4)*8 + i;
        int col = nt*16 + (lane & 15);
        float v = (k < CIN2 && col < 27) ? off2_w[((e*27 + col)*CIN2 + k)*9 + t] : 0.f;
        bf2[idx] = f2bfbits(v);
        return;
    }
    idx -= 110592;
    if (idx < 324) { o2b[idx] = off2_b[idx]; return; }
    idx -= 324;
    if (idx < 55296) {                       // ws2 [e][t][1][lane][i]  (COUT=10)
        int e = idx / 4608, r = idx % 4608;
        int t = r / 512, r3 = r % 512;
        int lane = r3 / 8, i = r3 % 8;
        int c = (lane >> 4)*8 + i;
        int o = lane & 15;
        float v = (c < CIN2 && o < NHID) ? dcn2_w[((e*10 + o)*CIN2 + c)*9 + t] : 0.f;
        ws2[idx] = f2bfbits(v);
        return;
    }
    idx -= 55296;
    if (idx < 15360) {                       // upd_wt [p][c][10]
        int p = idx / 2560, r = idx % 2560, c = r / 10, o = r % 10;
        uwt[idx] = upd_w[(p*10 + o)*256 + c];
        return;
    }
}

// ---------------------------------------------------------------------------
// bn_finish + reduce/stats kernels.
// ---------------------------------------------------------------------------
__device__ __forceinline__ void bn_finish(float s1, float s2, int n, float g, float bt,
                                          float* scale, float* shift, int idx)
{
    float mean = s1 / (float)n;
    float var  = fmaxf(s2 / (float)n - mean*mean, 0.f);
    float rs   = rsqrtf(var + 1e-5f);
    scale[idx] = g * rs;
    shift[idx] = bt - mean * g * rs;
}

// Reduce 288 per-wave partials (72 blocks x 4 waves) per (e,o).
template<int COUT>
__global__ __launch_bounds__(256)
void bn_reduce(const float* __restrict__ pu, const float* __restrict__ pq,
               const float* __restrict__ gamma, const float* __restrict__ beta,
               float* __restrict__ scale, float* __restrict__ shift)
{
    const int eo = blockIdx.x;
    const int e = eo / COUT, o = eo % COUT;
    float s1 = 0.f, s2 = 0.f;
    for (int j = threadIdx.x; j < 288; j += 256) {
        size_t idx = (size_t)(288*e + j)*COUT + o;
        s1 += pu[idx]; s2 += pq[idx];
    }
    __shared__ float r1[256], r2[256];
    r1[threadIdx.x] = s1; r2[threadIdx.x] = s2;
    __syncthreads();
    for (int s = 128; s > 0; s >>= 1) {
        if (threadIdx.x < s) { r1[threadIdx.x] += r1[threadIdx.x+s]; r2[threadIdx.x] += r2[threadIdx.x+s]; }
        __syncthreads();
    }
    if (threadIdx.x == 0)
        bn_finish(r1[0], r2[0], BB*HWD, gamma[eo], beta[eo], scale, shift, eo);
}

template<int C>
__global__ __launch_bounds__(256)
void bn_stats_flat(const float* __restrict__ x, const float* __restrict__ gamma,
                   const float* __restrict__ beta, float* __restrict__ scale,
                   float* __restrict__ shift)
{
    const int gc = blockIdx.x;
    const int g = gc / C, c = gc % C;
    const int N = BB * HWD;
    float s1 = 0.f, s2 = 0.f;
    for (int idx = threadIdx.x; idx < N; idx += 256) {
        int b = idx / HWD, p = idx % HWD;
        float v = x[((size_t)(g*BB + b)*C + c)*HWD + p];
        s1 += v; s2 += v*v;
    }
    __shared__ float r1[256], r2[256];
    r1[threadIdx.x] = s1; r2[threadIdx.x] = s2;
    __syncthreads();
    for (int s = 128; s > 0; s >>= 1) {
        if (threadIdx.x < s) { r1[threadIdx.x] += r1[threadIdx.x+s]; r2[threadIdx.x] += r2[threadIdx.x+s]; }
        __syncthreads();
    }
    if (threadIdx.x == 0)
        bn_finish(r1[0], r2[0], N, gamma[gc], beta[gc], scale, shift, gc);
}

// ---------------------------------------------------------------------------
// Fused DCNv2 layer: MFMA offset-conv + MFMA sampling matvec, wave-async;
// per-wave BN partial stats written non-atomically.
// grid: (36, B, E); LDS 40.6 KB.
// ---------------------------------------------------------------------------
template<int COUT, bool L1>
__global__ __launch_bounds__(256, 4)
void dcn_tiled(const float* __restrict__ xin_all,
               const float* __restrict__ xp,        // only for L1 gather
               const int* __restrict__ esrc, const int* __restrict__ edst,
               const unsigned short* __restrict__ bfr_all, // conv B [E][9][2][64][8]
               const float* __restrict__ bo_all,    // [E][27]
               const unsigned short* __restrict__ ws_all,  // samp B [E][9][NT][64][8]
               const float* __restrict__ bnS, const float* __restrict__ bnT,
               float* __restrict__ out,
               float* __restrict__ pSum, float* __restrict__ pSq)
{
    constexpr int NT = (COUT > 16) ? 2 : 1;
    const int b = blockIdx.y, e = blockIdx.z;
    const int ty0 = (blockIdx.x / 6) * 16, tx0 = (blockIdx.x % 6) * 16;
    const int tid = threadIdx.x;
    const int ly = tid >> 4, lx = tid & 15;
    const int h = ty0 + ly, w = tx0 + lx;
    const int r0 = ty0 - 2, c0 = tx0 - 2;            // staged box origin
    const int flat = blockIdx.x + 36*(b + BB*e);     // 0..863

    const float* __restrict__ xin = xin_all + (size_t)(e*BB + b)*CIN2*HWD;
    const float* __restrict__ bo  = bo_all + e*27;
    const unsigned short* __restrict__ bfr = bfr_all + (size_t)e*9216;
    const unsigned short* __restrict__ wsf = ws_all + (size_t)e*(9*NT*512);

    __shared__ unsigned short ldsb[3*GHALF];         // 20160 ushorts
    __shared__ unsigned short stile[256*SROW];       // 10240 ushorts = 20480 B

    // ---- stage bf16 tile: 3 groups x 420 pix x 8 ch ----
    #pragma unroll 1
    for (int i = tid; i < 3*NPIX; i += 256) {
        int g = i / NPIX;
        int pix = i - g*NPIX;
        int rr = pix / BCOL, cc = pix - rr*BCOL;
        int y = r0 + rr, x = c0 + cc;
        bool inb = (y >= 0 && y < HH && x >= 0 && x < WW);
        int hw = y*WW + x;
        unsigned int dpk[4];
        #pragma unroll
        for (int jj = 0; jj < 4; jj++) {
            unsigned int packed = 0;
            #pragma unroll
            for (int hl = 0; hl < 2; hl++) {
                int c = g*8 + jj*2 + hl;
                float v = 0.f;
                if (inb && c < CIN2) {
                    if (L1) {
                        int part = (c < NHID) ? esrc[e] : edst[e];
                        int ch   = (c < NHID) ? c : c - NHID;
                        v = xp[((size_t)(part*BB + b)*NHID + ch)*HWD + hw];
                    } else {
                        v = xin[(size_t)c*HWD + hw];
                        v = fmaxf(fmaf(v, bnS[e*CIN2 + c], bnT[e*CIN2 + c]), 0.f);
                    }
                }
                packed |= ((unsigned int)f2bfbits(v)) << (16*hl);
            }
            dpk[jj] = packed;
        }
        *reinterpret_cast<uint4*>(&ldsb[g*GHALF + pix*8]) =
            make_uint4(dpk[0], dpk[1], dpk[2], dpk[3]);
    }
    __syncthreads();     // the ONLY block-wide barrier (ldsb is cross-wave)

    const int lane = tid & 63;
    const int wv   = tid >> 6;
    const int lrow = lane & 15;
    const int lkg  = lane >> 4;

    // ---- offset conv via MFMA ----
    {
        const int gsel = (lkg < 3) ? lkg : 2;        // k>=24 lanes: B rows are 0
        f32x4 cacc[4][2];
        #pragma unroll
        for (int mt = 0; mt < 4; mt++)
            #pragma unroll
            for (int nt = 0; nt < 2; nt++)
                cacc[mt][nt] = f32x4{0.f, 0.f, 0.f, 0.f};

        const s16x8* ap = reinterpret_cast<const s16x8*>(&ldsb[gsel*GHALF]);
        #pragma unroll 1
        for (int t = 0; t < 9; t++) {
            const s16x8* bp = reinterpret_cast<const s16x8*>(bfr + t*1024);
            s16x8 b0 = bp[lane];
            s16x8 b1 = bp[64 + lane];
            int dty = t/3 - 1, dtx = t - (t/3)*3 - 1;
            #pragma unroll
            for (int mt = 0; mt < 4; mt++) {
                int pxl = wv*64 + mt*16 + lrow;
                int pix = ((pxl >> 4) + 2 + dty)*BCOL + ((pxl & 15) + 2 + dtx);
                s16x8 a = ap[pix];
                cacc[mt][0] = __builtin_amdgcn_mfma_f32_16x16x32_bf16(a, b0, cacc[mt][0], 0, 0, 0);
                cacc[mt][1] = __builtin_amdgcn_mfma_f32_16x16x32_bf16(a, b1, cacc[mt][1], 0, 0, 0);
            }
        }
        // write om tiles (C/D layout: col=lane&15, row=(lane>>4)*4+r)
        #pragma unroll
        for (int mt = 0; mt < 4; mt++)
            #pragma unroll
            for (int nt = 0; nt < 2; nt++)
                #pragma unroll
                for (int r = 0; r < 4; r++) {
                    int row = wv*64 + mt*16 + lkg*4 + r;
                    stile[row*SROW + nt*16 + lrow] = f2bfbits(cacc[mt][nt][r]);
                }
    }
    wave_lds_fence();

    // ---- unpack this pixel's om[27] (+bias); then zero cols 20..31 of row ----
    float om[27];
    {
        const uint4* orow = reinterpret_cast<const uint4*>(&stile[(size_t)tid*SROW]);
        uint4 u0 = orow[0], u1 = orow[1], u2 = orow[2], u3 = orow[3];
        unsigned int dwv[14] = {u0.x,u0.y,u0.z,u0.w, u1.x,u1.y,u1.z,u1.w,
                                u2.x,u2.y,u2.z,u2.w, u3.x,u3.y};
        #pragma unroll
        for (int o = 0; o < 27; o++) {
            unsigned int bits = (o & 1) ? (dwv[o>>1] >> 16) : (dwv[o>>1] & 0xffffu);
            om[o] = bfbits2f(bits) + bo[o];
        }
    }
    {
        unsigned short* mr = &stile[(size_t)tid*SROW];
        *reinterpret_cast<uint2*>(mr + 20) = make_uint2(0u, 0u);
        *reinterpret_cast<uint2*>(mr + 24) = make_uint2(0u, 0u);
        *reinterpret_cast<uint2*>(mr + 28) = make_uint2(0u, 0u);
    }

    // ---- sampling: per tap, scalar blend -> s-row -> wave fence -> MFMA ----
    f32x4 sacc[4][NT];
    #pragma unroll
    for (int mt = 0; mt < 4; mt++)
        #pragma unroll
        for (int nt = 0; nt < NT; nt++)
            sacc[mt][nt] = f32x4{0.f, 0.f, 0.f, 0.f};

    #pragma unroll
    for (int k = 0; k < 9; k++) {
        float m  = sigf(om[18 + k]);
        float ys = (float)(h + k/3 - 1) + om[2*k];
        float xs = (float)(w + k%3 - 1) + om[2*k + 1];
        float y0f = floorf(ys), x0f = floorf(xs);
        int iy = (int)y0f, ix = (int)x0f;
        float fy = ys - y0f, fx = xs - x0f;
        bool vy0 = (iy >= 0) && (iy < HH);
        bool vy1 = (iy >= -1) && (iy < HH-1);
        bool vx0 = (ix >= 0) && (ix < WW);
        bool vx1 = (ix >= -1) && (ix < WW-1);
        float w00 = (vy0 && vx0) ? (1.f-fy)*(1.f-fx)*m : 0.f;
        float w01 = (vy0 && vx1) ? (1.f-fy)*fx*m       : 0.f;
        float w10 = (vy1 && vx0) ? fy*(1.f-fx)*m       : 0.f;
        float w11 = (vy1 && vx1) ? fy*fx*m             : 0.f;
        int cy0 = min(max(iy,   0), HH-1), cy1 = min(max(iy+1, 0), HH-1);
        int cx0 = min(max(ix,   0), WW-1), cx1 = min(max(ix+1, 0), WW-1);

        unsigned int pk[10];
        bool staged = (cy0 >= r0) && (cy1 <= r0 + BOX-1) &&
                      (cx0 >= c0) && (cx1 <= c0 + BOX-1);
        if (staged) {
            const int p00 = (cy0-r0)*BCOL + (cx0-c0);
            const int p01 = (cy0-r0)*BCOL + (cx1-c0);
            const int p10 = (cy1-r0)*BCOL + (cx0-c0);
            const int p11 = (cy1-r0)*BCOL + (cx1-c0);
            #pragma unroll
            for (int g = 0; g < 3; g++) {
                const s16x8* gp = reinterpret_cast<const s16x8*>(&ldsb[g*GHALF]);
                s16x8 a8 = gp[p00], b8 = gp[p01], c8 = gp[p10], d8 = gp[p11];
                #pragma unroll
                for (int jp = 0; jp < 4; jp++) {
                    if (g*8 + jp*2 < CIN2) {
                        float s0, s1;
                        {
                            int j = jp*2;
                            float av = bfbits2f((unsigned short)a8[j]);
                            float bv = bfbits2f((unsigned short)b8[j]);
                            float cv = bfbits2f((unsigned short)c8[j]);
                            float dv = bfbits2f((unsigned short)d8[j]);
                            s0 = w00*av + w01*bv + w10*cv + w11*dv;
                        }
                        {
                            int j = jp*2 + 1;
                            float av = bfbits2f((unsigned short)a8[j]);
                            float bv = bfbits2f((unsigned short)b8[j]);
                            float cv = bfbits2f((unsigned short)c8[j]);
                            float dv = bfbits2f((unsigned short)d8[j]);
                            s1 = w00*av + w01*bv + w10*cv + w11*dv;
                        }
                        pk[g*4 + jp] = (unsigned int)f2bfbits(s0)
                                     | ((unsigned int)f2bfbits(s1) << 16);
                    }
                }
            }
        } else {
            int o00 = cy0*WW + cx0, o01 = cy0*WW + cx1;
            int o10 = cy1*WW + cx0, o11 = cy1*WW + cx1;
            float sv[20];
            #pragma unroll
            for (int c = 0; c < CIN2; c++) {
                const float* src;
                float sc = 1.f, sh = 0.f;
                if (L1) {
                    int part = (c < NHID) ? esrc[e] : edst[e];
                    int ch   = (c < NHID) ? c : c - NHID;
                    src = xp + ((size_t)(part*BB + b)*NHID + ch)*HWD;
                } else {
                    src = xin + (size_t)c*HWD;
                    sc = bnS[e*CIN2 + c]; sh = bnT[e*CIN2 + c];
                }
                float av = src[o00], bv = src[o01], cv = src[o10], dv = src[o11];
                if (!L1) {
                    av = fmaxf(fmaf(av, sc, sh), 0.f); bv = fmaxf(fmaf(bv, sc, sh), 0.f);
                    cv = fmaxf(fmaf(cv, sc, sh), 0.f); dv = fmaxf(fmaf(dv, sc, sh), 0.f);
                }
                sv[c] = w00*av + w01*bv + w10*cv + w11*dv;
            }
            #pragma unroll
            for (int jp = 0; jp < 10; jp++)
                pk[jp] = (unsigned int)f2bfbits(sv[2*jp])
                       | ((unsigned int)f2bfbits(sv[2*jp+1]) << 16);
        }

        {   // write own s-row (wave-private)
            unsigned short* mr = &stile[(size_t)tid*SROW];
            *reinterpret_cast<uint4*>(mr)      = make_uint4(pk[0], pk[1], pk[2], pk[3]);
            *reinterpret_cast<uint4*>(mr + 8)  = make_uint4(pk[4], pk[5], pk[6], pk[7]);
            *reinterpret_cast<uint2*>(mr + 16) = make_uint2(pk[8], pk[9]);
        }
        wave_lds_fence();

        // MFMA: acc[pixel][o] += s[pixel][c] * Wd[c][o]  (reads wave-own rows)
        {
            const s16x8* wsp = reinterpret_cast<const s16x8*>(wsf + (size_t)k*NT*512);
            s16x8 wb0 = wsp[lane];
            s16x8 wb1{};
            if constexpr (NT == 2) wb1 = wsp[64 + lane];
            #pragma unroll
            for (int mt = 0; mt < 4; mt++) {
                int pxl = wv*64 + mt*16 + lrow;
                s16x8 a = *reinterpret_cast<const s16x8*>(&stile[pxl*SROW + lkg*8]);
                sacc[mt][0] = __builtin_amdgcn_mfma_f32_16x16x32_bf16(a, wb0, sacc[mt][0], 0, 0, 0);
                if constexpr (NT == 2)
                    sacc[mt][1] = __builtin_amdgcn_mfma_f32_16x16x32_bf16(a, wb1, sacc[mt][1], 0, 0, 0);
            }
        }
        wave_lds_fence();   // A-reads drained before next tap's s-row write
    }

    // ---- per-wave BN partials (2-shuffle reduce, NON-atomic store) ----
    #pragma unroll
    for (int nt = 0; nt < NT; nt++) {
        int o = nt*16 + lrow;
        float ls = 0.f, lq = 0.f;
        #pragma unroll
        for (int mt = 0; mt < 4; mt++)
            #pragma unroll
            for (int r = 0; r < 4; r++) {
                float v = sacc[mt][nt][r];
                ls += v; lq += v*v;
            }
        ls += __shfl_xor(ls, 16); lq += __shfl_xor(lq, 16);
        ls += __shfl_xor(ls, 32); lq += __shfl_xor(lq, 32);
        if (lkg == 0 && o < COUT) {
            size_t pidx = (size_t)(flat*4 + wv)*COUT + o;
            pSum[pidx] = ls;
            pSq[pidx]  = lq;
        }
    }

    // ---- writeout: wave-quartered LDS bounce, then coalesced stores ----
    {
        float* ldsf = reinterpret_cast<float*>(stile) + wv*1280;  // 5120 B/wave
        #pragma unroll
        for (int mt = 0; mt < 4; mt++) {
            #pragma unroll
            for (int nt = 0; nt < NT; nt++) {
                int o = nt*16 + lrow;
                if (o < COUT) {
                    #pragma unroll
                    for (int r = 0; r < 4; r++) {
                        int lp = mt*16 + lkg*4 + r;          // 0..63 in-wave pixel
                        ldsf[o*64 + lp] = sacc[mt][nt][r];
                    }
                }
            }
        }
        wave_lds_fence();
        float* op = out + (size_t)(e*BB + b)*COUT*HWD + h*WW + w;
        #pragma unroll
        for (int o = 0; o < COUT; o++)
            op[(size_t)o*HWD] = ldsf[o*64 + (tid & 63)];
    }
}

// ---------------------------------------------------------------------------
// Fused msg + gate + q, 512-thread c-split:
//   half A (tid<256): channels 0-127 of the 256->10 projection + gate
//   half B          : channels 128-255, partial acc -> LDS
// grid: (36, B, P)
// ---------------------------------------------------------------------------
__global__ __launch_bounds__(512)
void mgq_kernel(const float* __restrict__ t2all, const float* __restrict__ s2,
                const float* __restrict__ sh2, const float* __restrict__ o_w,
                const float* __restrict__ o_b, const float* __restrict__ a_w,
                const float* __restrict__ a_b, const float* __restrict__ xp,
                const float* __restrict__ xh,
                const float* __restrict__ att_w, const float* __restrict__ att_b,
                const float* __restrict__ du_w, const float* __restrict__ du_b,
                const float* __restrict__ dl_w, const float* __restrict__ dl_b,
                const int* __restrict__ esrc, const int* __restrict__ edst,
                const float* __restrict__ p_fea, const float* __restrict__ wq_all,
                float* __restrict__ y)
{
    const int sub  = threadIdx.x & 255;
    const int half = threadIdx.x >> 8;
    const int px = blockIdx.x * 256 + sub;
    const int b = blockIdx.y, p = blockIdx.z;

    __shared__ float red[256][NHID];     // half B partials (10 KB)

    // ---- partial 256->10 projection over this half's 128 channels ----
    const float* wq = wq_all + (size_t)p*NIN*NHID;
    const float* pf = p_fea + (size_t)b*NIN*HWD + px;
    float acc[NHID];
    #pragma unroll
    for (int o = 0; o < NHID; o++) acc[o] = 0.f;
    const int cb = half*128;
    for (int c = cb; c < cb + 128; c += 8) {
        float v0 = pf[(size_t)(c+0)*HWD];
        float v1 = pf[(size_t)(c+1)*HWD];
        float v2 = pf[(size_t)(c+2)*HWD];
        float v3 = pf[(size_t)(c+3)*HWD];
        float v4 = pf[(size_t)(c+4)*HWD];
        float v5 = pf[(size_t)(c+5)*HWD];
        float v6 = pf[(size_t)(c+6)*HWD];
        float v7 = pf[(size_t)(c+7)*HWD];
        const float* wc = wq + c*NHID;
        #pragma unroll
        for (int o = 0; o < NHID; o++) acc[o] = fmaf(v0, wc[o], acc[o]);
        #pragma unroll
        for (int o = 0; o < NHID; o++) acc[o] = fmaf(v1, wc[NHID + o], acc[o]);
        #pragma unroll
        for (int o = 0; o < NHID; o++) acc[o] = fmaf(v2, wc[2*NHID + o], acc[o]);
        #pragma unroll
        for (int o = 0; o < NHID; o++) acc[o] = fmaf(v3, wc[3*NHID + o], acc[o]);
        #pragma unroll
        for (int o = 0; o < NHID; o++) acc[o] = fmaf(v4, wc[4*NHID + o], acc[o]);
        #pragma unroll
        for (int o = 0; o < NHID; o++) acc[o] = fmaf(v5, wc[5*NHID + o], acc[o]);
        #pragma unroll
        for (int o = 0; o < NHID; o++) acc[o] = fmaf(v6, wc[6*NHID + o], acc[o]);
        #pragma unroll
        for (int o = 0; o < NHID; o++) acc[o] = fmaf(v7, wc[7*NHID + o], acc[o]);
    }

    if (half == 1) {
        #pragma unroll
        for (int o = 0; o < NHID; o++) red[sub][o] = acc[o];
    }

    // ---- half A computes the gate while half B's stores land ----
    float gate = 0.f;
    if (half == 0) {
        float s = att_b[p];
        #pragma unroll
        for (int c = 0; c < NHID; c++)
            s += xp[((size_t)(p*BB + b)*NHID + c)*HWD + px] * att_w[p*NHID + c];
        float satt = sigf(s);

        int hs = (p < 4) ? 0 : 1;
        const float* dw = (p < 4) ? du_w : dl_w;
        float d = (p < 4) ? du_b[0] : dl_b[0];
        #pragma unroll
        for (int c = 0; c < NHID; c++)
            d += xh[((size_t)(hs*BB + b)*NHID + c)*HWD + px] * dw[c];
        float dec = sigf(d);

        float xpp = 0.f;
        for (int e = 0; e < NE; e++) {
            if (edst[e] != p) continue;
            float sab = o_b[e];
            #pragma unroll
            for (int c = 0; c < NHID; c++) {
                float v = t2all[((size_t)(e*BB + b)*NHID + c)*HWD + px];
                v = fmaxf(fmaf(v, s2[e*NHID+c], sh2[e*NHID+c]), 0.f);
                sab += v * o_w[e*NHID + c];
            }
            int sp = esrc[e];
            float sa = a_b[e];
            #pragma unroll
            for (int c = 0; c < NHID; c++)
                sa += xp[((size_t)(sp*BB + b)*NHID + c)*HWD + px] * a_w[e*NHID + c];
            xpp += sigf(sab) * (1.f - sigf(sa));
        }
        gate = 1.f + dec + satt + xpp;
    }
    __syncthreads();

    if (half == 0) {
        float* yp = y + ((size_t)(p*BB + b)*NHID)*HWD + px;
        #pragma unroll
        for (int o = 0; o < NHID; o++)
            yp[(size_t)o*HWD] = (acc[o] + red[sub][o]) * gate;
    }
}

// ---------------------------------------------------------------------------
// out = relu(bn5(y));   grid: (36, B*HID, P)
// ---------------------------------------------------------------------------
__global__ __launch_bounds__(256)
void out_kernel(const float* __restrict__ y, const float* __restrict__ s5,
                const float* __restrict__ t5, float* __restrict__ out)
{
    int px = blockIdx.x * 256 + threadIdx.x;
    int bo = blockIdx.y, p = blockIdx.z;
    int b = bo / NHID, o = bo % NHID;
    size_t idx = ((size_t)(p*BB + b)*NHID + o)*HWD + px;
    out[idx] = fmaxf(fmaf(y[idx], s5[p*NHID+o], t5[p*NHID+o]), 0.f);
}

// ---------------------------------------------------------------------------
// launcher
// ---------------------------------------------------------------------------
extern "C" void kernel_launch(void* const* d_in, const int* in_sizes, int n_in,
                              void* d_out, int out_size, void* d_ws, size_t ws_size,
                              hipStream_t stream)
{
    (void)in_sizes; (void)n_in; (void)out_size; (void)ws_size;

    const float* p_fea  = (const float*)d_in[0];
    const float* xp     = (const float*)d_in[1];
    const float* xh     = (const float*)d_in[2];
    const float* att_w  = (const float*)d_in[3];
    const float* att_b  = (const float*)d_in[4];
    const float* du_w   = (const float*)d_in[5];
    const float* du_b   = (const float*)d_in[6];
    const float* dl_w   = (const float*)d_in[7];
    const float* dl_b   = (const float*)d_in[8];
    const float* upd_w  = (const float*)d_in[9];
    const float* upd_g  = (const float*)d_in[10];
    const float* upd_b  = (const float*)d_in[11];
    const float* off1_w = (const float*)d_in[12];
    const float* off1_b = (const float*)d_in[13];
    const float* dcn1_w = (const float*)d_in[14];
    const float* bn1_g  = (const float*)d_in[15];
    const float* bn1_b  = (const float*)d_in[16];
    const float* off2_w = (const float*)d_in[17];
    const float* off2_b = (const float*)d_in[18];
    const float* dcn2_w = (const float*)d_in[19];
    const float* bn2_g  = (const float*)d_in[20];
    const float* bn2_b  = (const float*)d_in[21];
    const float* out_w  = (const float*)d_in[22];
    const float* out_b  = (const float*)d_in[23];
    const float* aatt_w = (const float*)d_in[24];
    const float* aatt_b = (const float*)d_in[25];
    const int* esrc     = (const int*)d_in[26];
    const int* edst     = (const int*)d_in[27];
    float* outp = (float*)d_out;
    float* ws = (float*)d_ws;

    // workspace layout (float offsets; ushort arrays occupy half-floats)
    constexpr size_t o_x1   = 0;                                    // [E][B][20][HWD]
    constexpr size_t o_t2   = o_x1  + (size_t)NE*BB*CIN2*HWD;       // [E][B][10][HWD]
    constexpr size_t o_bf1  = o_t2  + (size_t)NE*BB*NHID*HWD;       // 110592 ush
    constexpr size_t o_b1   = o_bf1 + 55296;
    constexpr size_t o_ws1  = o_b1  + 324;                          // 110592 ush
    constexpr size_t o_bf2  = o_ws1 + 55296;                        // 110592 ush
    constexpr size_t o_b2   = o_bf2 + 55296;
    constexpr size_t o_ws2  = o_b2  + 324;                          // 55296 ush
    constexpr size_t o_uw   = o_ws2 + 27648;
    constexpr size_t o_bn1s = o_uw  + 15360;
    constexpr size_t o_bn1t = o_bn1s + NE*CIN2;
    constexpr size_t o_bn2s = o_bn1t + NE*CIN2;
    constexpr size_t o_bn2t = o_bn2s + NE*NHID;
    constexpr size_t o_bn5s = o_bn2t + NE*NHID;
    constexpr size_t o_bn5t = o_bn5s + NPART*NHID;
    // per-wave BN partials (fully overwritten each call; no zeroing needed)
    constexpr size_t o_p1u  = o_bn5t + NPART*NHID;   // [3456][20]
    constexpr size_t o_p1q  = o_p1u + 3456*20;
    constexpr size_t o_p2u  = o_p1q + 3456*20;       // [3456][10]
    constexpr size_t o_p2q  = o_p2u + 3456*10;
    constexpr size_t o_y    = o_p2q + 3456*10;                      // [P][B][10][HWD]
    float* x1 = ws + o_x1;
    float* t2 = ws + o_t2;
    float* y  = ws + o_y;
    unsigned short* bf1 = (unsigned short*)(ws + o_bf1);
    unsigned short* ws1 = (unsigned short*)(ws + o_ws1);
    unsigned short* bf2 = (unsigned short*)(ws + o_bf2);
    unsigned short* ws2 = (unsigned short*)(ws + o_ws2);

    // items: 403080 -> 1575 blocks
    xpose_weights<<<dim3(1575), 256, 0, stream>>>(
        off1_w, off1_b, dcn1_w, off2_w, off2_b, dcn2_w, upd_w,
        bf1, ws+o_b1, ws1, bf2, ws+o_b2, ws2, ws+o_uw);

    dcn_tiled<CIN2, true><<<dim3(36, BB, NE), 256, 0, stream>>>(
        nullptr, xp, esrc, edst, bf1, ws+o_b1, ws1,
        nullptr, nullptr, x1, ws+o_p1u, ws+o_p1q);

    bn_reduce<CIN2><<<dim3(NE*CIN2), 256, 0, stream>>>(
        ws+o_p1u, ws+o_p1q, bn1_g, bn1_b, ws+o_bn1s, ws+o_bn1t);

    dcn_tiled<NHID, false><<<dim3(36, BB, NE), 256, 0, stream>>>(
        x1, nullptr, esrc, edst, bf2, ws+o_b2, ws2,
        ws+o_bn1s, ws+o_bn1t, t2, ws+o_p2u, ws+o_p2q);

    bn_reduce<NHID><<<dim3(NE*NHID), 256, 0, stream>>>(
        ws+o_p2u, ws+o_p2q, bn2_g, bn2_b, ws+o_bn2s, ws+o_bn2t);

    mgq_kernel<<<dim3(36, BB, NPART), 512, 0, stream>>>(
        t2, ws+o_bn2s, ws+o_bn2t, out_w, out_b, aatt_w, aatt_b, xp, xh,
        att_w, att_b, du_w, du_b, dl_w, dl_b, esrc, edst,
        p_fea, ws+o_uw, y);

    bn_stats_flat<NHID><<<dim3(NPART*NHID), 256, 0, stream>>>(
        y, upd_g, upd_b, ws+o_bn5s, ws+o_bn5t);

    out_kernel<<<dim3(36, BB*NHID, NPART), 256, 0, stream>>>(
        y, ws+o_bn5s, ws+o_bn5t, outp);
}

// Round 20
// 155.151 us; speedup vs baseline: 1.0996x; 1.0996x over previous
//
#include <hip/hip_runtime.h>
#include <hip/hip_bf16.h>

// ---------------------------------------------------------------------------
// Part_Graph: deformable-conv message passing over a 6-node part graph.
// B=2, H=W=96, IN=256, HID=10, P=6, E=12, K=9 taps.  ALL I/O is float32.
// dcn: offset-conv AND sampling tap-matvec via bf16 MFMA (16x16x32).
// BN1/BN2 stats: per-wave NON-ATOMIC partials + tiny tree-reduce kernel.
// mgq: 256-thread, 8-deep load batching (proven best R18 configuration).
// ---------------------------------------------------------------------------

#define NE 12
#define NPART 6
#define BB 2
#define HH 96
#define WW 96
#define HWD (HH*WW)          // 9216
#define CIN2 20              // 2*HID concat channels
#define NHID 10
#define NIN 256

// LDS tile geometry: 16x16 output tile, +-2 halo -> 20x20 box.
#define BOX 20
#define BCOL 21              // pix = rr*BCOL + cc
#define NPIX (BOX*BCOL)      // 420
#define GHALF (NPIX*8)       // ushorts per 8-channel group = 3360
#define SROW 40              // s-tile row stride (ushorts): 80 B, 16B-aligned

typedef __attribute__((ext_vector_type(8))) short s16x8;
typedef __attribute__((ext_vector_type(4))) float f32x4;

__device__ __forceinline__ float sigf(float x) { return 1.f / (1.f + __expf(-x)); }
__device__ __forceinline__ float bfbits2f(unsigned int u) {
    return __uint_as_float(u << 16);
}
__device__ __forceinline__ unsigned short f2bfbits(float v) {
    __hip_bfloat16 h = __float2bfloat16(v);
    return *reinterpret_cast<unsigned short*>(&h);
}
// Intra-wave LDS fence (guide rule #18).
__device__ __forceinline__ void wave_lds_fence() {
    asm volatile("s_waitcnt lgkmcnt(0)" ::: "memory");
    __builtin_amdgcn_sched_barrier(0);
}

// ---------------------------------------------------------------------------
// Weight prep (bf16 MFMA B-fragments + fp32 bias + fp32 upd).
// ---------------------------------------------------------------------------
__global__ __launch_bounds__(256)
void xpose_weights(const float* __restrict__ off1_w, const float* __restrict__ off1_b,
                   const float* __restrict__ dcn1_w,
                   const float* __restrict__ off2_w, const float* __restrict__ off2_b,
                   const float* __restrict__ dcn2_w,
                   const float* __restrict__ upd_w,
                   unsigned short* __restrict__ bf1, float* __restrict__ o1b,
                   unsigned short* __restrict__ ws1,
                   unsigned short* __restrict__ bf2, float* __restrict__ o2b,
                   unsigned short* __restrict__ ws2,
                   float* __restrict__ uwt)
{
    int idx = blockIdx.x * 256 + threadIdx.x;
    if (idx < 110592) {                      // bf1 [e][t][nt][lane][i]
        int e = idx / 9216, r = idx % 9216;
        int t = r / 1024, r2 = r % 1024;
        int nt = r2 / 512, r3 = r2 % 512;
        int lane = r3 / 8, i = r3 % 8;
        int k = (lane >> 4)*8 + i;
        int col = nt*16 + (lane & 15);
        float v = (k < CIN2 && col < 27) ? off1_w[((e*27 + col)*CIN2 + k)*9 + t] : 0.f;
        bf1[idx] = f2bfbits(v);
        return;
    }
    idx -= 110592;
    if (idx < 324) { o1b[idx] = off1_b[idx]; return; }
    idx -= 324;
    if (idx < 110592) {                      // ws1 [e][t][nt][lane][i]  (COUT=20)
        int e = idx / 9216, r = idx % 9216;
        int t = r / 1024, r2 = r % 1024;
        int nt = r2 / 512, r3 = r2 % 512;
        int lane = r3 / 8, i = r3 % 8;
        int c = (lane >> 4)*8 + i;
        int o = nt*16 + (lane & 15);
        float v = (c < CIN2 && o < CIN2) ? dcn1_w[((e*20 + o)*CIN2 + c)*9 + t] : 0.f;
        ws1[idx] = f2bfbits(v);
        return;
    }
    idx -= 110592;
    if (idx < 110592) {                      // bf2
        int e = idx / 9216, r = idx % 9216;
        int t = r / 1024, r2 = r % 1024;
        int nt = r2 / 512, r3 = r2 % 512;
        int lane = r3 / 8, i = r3 % 8;
        int k = (lane >> 4)*8 + i;
        int col = nt*16 + (lane & 15);
        float v = (k < CIN2 && col < 27) ? off2_w[((e*27 + col)*CIN2 + k)*9 + t] : 0.f;
        bf2[idx] = f2bfbits(v);
        return;
    }
    idx -= 110592;
    if (idx < 324) { o2b[idx] = off2_b[idx]; return; }
    idx -= 324;
    if (idx < 55296) {                       // ws2 [e][t][1][lane][i]  (COUT=10)
        int e = idx / 4608, r = idx % 4608;
        int t = r / 512, r3 = r % 512;
        int lane = r3 / 8, i = r3 % 8;
        int c = (lane >> 4)*8 + i;
        int o = lane & 15;
        float v = (c < CIN2 && o < NHID) ? dcn2_w[((e*10 + o)*CIN2 + c)*9 + t] : 0.f;
        ws2[idx] = f2bfbits(v);
        return;
    }
    idx -= 55296;
    if (idx < 15360) {                       // upd_wt [p][c][10]
        int p = idx / 2560, r = idx % 2560, c = r / 10, o = r % 10;
        uwt[idx] = upd_w[(p*10 + o)*256 + c];
        return;
    }
}

// ---------------------------------------------------------------------------
// bn_finish + reduce/stats kernels.
// ---------------------------------------------------------------------------
__device__ __forceinline__ void bn_finish(float s1, float s2, int n, float g, float bt,
                                          float* scale, float* shift, int idx)
{
    float mean = s1 / (float)n;
    float var  = fmaxf(s2 / (float)n - mean*mean, 0.f);
    float rs   = rsqrtf(var + 1e-5f);
    scale[idx] = g * rs;
    shift[idx] = bt - mean * g * rs;
}

// Reduce 288 per-wave partials (72 blocks x 4 waves) per (e,o).
template<int COUT>
__global__ __launch_bounds__(256)
void bn_reduce(const float* __restrict__ pu, const float* __restrict__ pq,
               const float* __restrict__ gamma, const float* __restrict__ beta,
               float* __restrict__ scale, float* __restrict__ shift)
{
    const int eo = blockIdx.x;
    const int e = eo / COUT, o = eo % COUT;
    float s1 = 0.f, s2 = 0.f;
    for (int j = threadIdx.x; j < 288; j += 256) {
        size_t idx = (size_t)(288*e + j)*COUT + o;
        s1 += pu[idx]; s2 += pq[idx];
    }
    __shared__ float r1[256], r2[256];
    r1[threadIdx.x] = s1; r2[threadIdx.x] = s2;
    __syncthreads();
    for (int s = 128; s > 0; s >>= 1) {
        if (threadIdx.x < s) { r1[threadIdx.x] += r1[threadIdx.x+s]; r2[threadIdx.x] += r2[threadIdx.x+s]; }
        __syncthreads();
    }
    if (threadIdx.x == 0)
        bn_finish(r1[0], r2[0], BB*HWD, gamma[eo], beta[eo], scale, shift, eo);
}

template<int C>
__global__ __launch_bounds__(256)
void bn_stats_flat(const float* __restrict__ x, const float* __restrict__ gamma,
                   const float* __restrict__ beta, float* __restrict__ scale,
                   float* __restrict__ shift)
{
    const int gc = blockIdx.x;
    const int g = gc / C, c = gc % C;
    const int N = BB * HWD;
    float s1 = 0.f, s2 = 0.f;
    for (int idx = threadIdx.x; idx < N; idx += 256) {
        int b = idx / HWD, p = idx % HWD;
        float v = x[((size_t)(g*BB + b)*C + c)*HWD + p];
        s1 += v; s2 += v*v;
    }
    __shared__ float r1[256], r2[256];
    r1[threadIdx.x] = s1; r2[threadIdx.x] = s2;
    __syncthreads();
    for (int s = 128; s > 0; s >>= 1) {
        if (threadIdx.x < s) { r1[threadIdx.x] += r1[threadIdx.x+s]; r2[threadIdx.x] += r2[threadIdx.x+s]; }
        __syncthreads();
    }
    if (threadIdx.x == 0)
        bn_finish(r1[0], r2[0], N, gamma[gc], beta[gc], scale, shift, gc);
}

// ---------------------------------------------------------------------------
// Fused DCNv2 layer: MFMA offset-conv + MFMA sampling matvec, wave-async;
// per-wave BN partial stats written non-atomically.
// grid: (36, B, E); LDS 40.6 KB.
// ---------------------------------------------------------------------------
template<int COUT, bool L1>
__global__ __launch_bounds__(256, 4)
void dcn_tiled(const float* __restrict__ xin_all,
               const float* __restrict__ xp,        // only for L1 gather
               const int* __restrict__ esrc, const int* __restrict__ edst,
               const unsigned short* __restrict__ bfr_all, // conv B [E][9][2][64][8]
               const float* __restrict__ bo_all,    // [E][27]
               const unsigned short* __restrict__ ws_all,  // samp B [E][9][NT][64][8]
               const float* __restrict__ bnS, const float* __restrict__ bnT,
               float* __restrict__ out,
               float* __restrict__ pSum, float* __restrict__ pSq)
{
    constexpr int NT = (COUT > 16) ? 2 : 1;
    const int b = blockIdx.y, e = blockIdx.z;
    const int ty0 = (blockIdx.x / 6) * 16, tx0 = (blockIdx.x % 6) * 16;
    const int tid = threadIdx.x;
    const int ly = tid >> 4, lx = tid & 15;
    const int h = ty0 + ly, w = tx0 + lx;
    const int r0 = ty0 - 2, c0 = tx0 - 2;            // staged box origin
    const int flat = blockIdx.x + 36*(b + BB*e);     // 0..863

    const float* __restrict__ xin = xin_all + (size_t)(e*BB + b)*CIN2*HWD;
    const float* __restrict__ bo  = bo_all + e*27;
    const unsigned short* __restrict__ bfr = bfr_all + (size_t)e*9216;
    const unsigned short* __restrict__ wsf = ws_all + (size_t)e*(9*NT*512);

    __shared__ unsigned short ldsb[3*GHALF];         // 20160 ushorts
    __shared__ unsigned short stile[256*SROW];       // 10240 ushorts = 20480 B

    // ---- stage bf16 tile: 3 groups x 420 pix x 8 ch ----
    #pragma unroll 1
    for (int i = tid; i < 3*NPIX; i += 256) {
        int g = i / NPIX;
        int pix = i - g*NPIX;
        int rr = pix / BCOL, cc = pix - rr*BCOL;
        int y = r0 + rr, x = c0 + cc;
        bool inb = (y >= 0 && y < HH && x >= 0 && x < WW);
        int hw = y*WW + x;
        unsigned int dpk[4];
        #pragma unroll
        for (int jj = 0; jj < 4; jj++) {
            unsigned int packed = 0;
            #pragma unroll
            for (int hl = 0; hl < 2; hl++) {
                int c = g*8 + jj*2 + hl;
                float v = 0.f;
                if (inb && c < CIN2) {
                    if (L1) {
                        int part = (c < NHID) ? esrc[e] : edst[e];
                        int ch   = (c < NHID) ? c : c - NHID;
                        v = xp[((size_t)(part*BB + b)*NHID + ch)*HWD + hw];
                    } else {
                        v = xin[(size_t)c*HWD + hw];
                        v = fmaxf(fmaf(v, bnS[e*CIN2 + c], bnT[e*CIN2 + c]), 0.f);
                    }
                }
                packed |= ((unsigned int)f2bfbits(v)) << (16*hl);
            }
            dpk[jj] = packed;
        }
        *reinterpret_cast<uint4*>(&ldsb[g*GHALF + pix*8]) =
            make_uint4(dpk[0], dpk[1], dpk[2], dpk[3]);
    }
    __syncthreads();     // the ONLY block-wide barrier (ldsb is cross-wave)

    const int lane = tid & 63;
    const int wv   = tid >> 6;
    const int lrow = lane & 15;
    const int lkg  = lane >> 4;

    // ---- offset conv via MFMA ----
    {
        const int gsel = (lkg < 3) ? lkg : 2;        // k>=24 lanes: B rows are 0
        f32x4 cacc[4][2];
        #pragma unroll
        for (int mt = 0; mt < 4; mt++)
            #pragma unroll
            for (int nt = 0; nt < 2; nt++)
                cacc[mt][nt] = f32x4{0.f, 0.f, 0.f, 0.f};

        const s16x8* ap = reinterpret_cast<const s16x8*>(&ldsb[gsel*GHALF]);
        #pragma unroll 1
        for (int t = 0; t < 9; t++) {
            const s16x8* bp = reinterpret_cast<const s16x8*>(bfr + t*1024);
            s16x8 b0 = bp[lane];
            s16x8 b1 = bp[64 + lane];
            int dty = t/3 - 1, dtx = t - (t/3)*3 - 1;
            #pragma unroll
            for (int mt = 0; mt < 4; mt++) {
                int pxl = wv*64 + mt*16 + lrow;
                int pix = ((pxl >> 4) + 2 + dty)*BCOL + ((pxl & 15) + 2 + dtx);
                s16x8 a = ap[pix];
                cacc[mt][0] = __builtin_amdgcn_mfma_f32_16x16x32_bf16(a, b0, cacc[mt][0], 0, 0, 0);
                cacc[mt][1] = __builtin_amdgcn_mfma_f32_16x16x32_bf16(a, b1, cacc[mt][1], 0, 0, 0);
            }
        }
        // write om tiles (C/D layout: col=lane&15, row=(lane>>4)*4+r)
        #pragma unroll
        for (int mt = 0; mt < 4; mt++)
            #pragma unroll
            for (int nt = 0; nt < 2; nt++)
                #pragma unroll
                for (int r = 0; r < 4; r++) {
                    int row = wv*64 + mt*16 + lkg*4 + r;
                    stile[row*SROW + nt*16 + lrow] = f2bfbits(cacc[mt][nt][r]);
                }
    }
    wave_lds_fence();

    // ---- unpack this pixel's om[27] (+bias); then zero cols 20..31 of row ----
    float om[27];
    {
        const uint4* orow = reinterpret_cast<const uint4*>(&stile[(size_t)tid*SROW]);
        uint4 u0 = orow[0], u1 = orow[1], u2 = orow[2], u3 = orow[3];
        unsigned int dwv[14] = {u0.x,u0.y,u0.z,u0.w, u1.x,u1.y,u1.z,u1.w,
                                u2.x,u2.y,u2.z,u2.w, u3.x,u3.y};
        #pragma unroll
        for (int o = 0; o < 27; o++) {
            unsigned int bits = (o & 1) ? (dwv[o>>1] >> 16) : (dwv[o>>1] & 0xffffu);
            om[o] = bfbits2f(bits) + bo[o];
        }
    }
    {
        unsigned short* mr = &stile[(size_t)tid*SROW];
        *reinterpret_cast<uint2*>(mr + 20) = make_uint2(0u, 0u);
        *reinterpret_cast<uint2*>(mr + 24) = make_uint2(0u, 0u);
        *reinterpret_cast<uint2*>(mr + 28) = make_uint2(0u, 0u);
    }

    // ---- sampling: per tap, scalar blend -> s-row -> wave fence -> MFMA ----
    f32x4 sacc[4][NT];
    #pragma unroll
    for (int mt = 0; mt < 4; mt++)
        #pragma unroll
        for (int nt = 0; nt < NT; nt++)
            sacc[mt][nt] = f32x4{0.f, 0.f, 0.f, 0.f};

    #pragma unroll
    for (int k = 0; k < 9; k++) {
        float m  = sigf(om[18 + k]);
        float ys = (float)(h + k/3 - 1) + om[2*k];
        float xs = (float)(w + k%3 - 1) + om[2*k + 1];
        float y0f = floorf(ys), x0f = floorf(xs);
        int iy = (int)y0f, ix = (int)x0f;
        float fy = ys - y0f, fx = xs - x0f;
        bool vy0 = (iy >= 0) && (iy < HH);
        bool vy1 = (iy >= -1) && (iy < HH-1);
        bool vx0 = (ix >= 0) && (ix < WW);
        bool vx1 = (ix >= -1) && (ix < WW-1);
        float w00 = (vy0 && vx0) ? (1.f-fy)*(1.f-fx)*m : 0.f;
        float w01 = (vy0 && vx1) ? (1.f-fy)*fx*m       : 0.f;
        float w10 = (vy1 && vx0) ? fy*(1.f-fx)*m       : 0.f;
        float w11 = (vy1 && vx1) ? fy*fx*m             : 0.f;
        int cy0 = min(max(iy,   0), HH-1), cy1 = min(max(iy+1, 0), HH-1);
        int cx0 = min(max(ix,   0), WW-1), cx1 = min(max(ix+1, 0), WW-1);

        unsigned int pk[10];
        bool staged = (cy0 >= r0) && (cy1 <= r0 + BOX-1) &&
                      (cx0 >= c0) && (cx1 <= c0 + BOX-1);
        if (staged) {
            const int p00 = (cy0-r0)*BCOL + (cx0-c0);
            const int p01 = (cy0-r0)*BCOL + (cx1-c0);
            const int p10 = (cy1-r0)*BCOL + (cx0-c0);
            const int p11 = (cy1-r0)*BCOL + (cx1-c0);
            #pragma unroll
            for (int g = 0; g < 3; g++) {
                const s16x8* gp = reinterpret_cast<const s16x8*>(&ldsb[g*GHALF]);
                s16x8 a8 = gp[p00], b8 = gp[p01], c8 = gp[p10], d8 = gp[p11];
                #pragma unroll
                for (int jp = 0; jp < 4; jp++) {
                    if (g*8 + jp*2 < CIN2) {
                        float s0, s1;
                        {
                            int j = jp*2;
                            float av = bfbits2f((unsigned short)a8[j]);
                            float bv = bfbits2f((unsigned short)b8[j]);
                            float cv = bfbits2f((unsigned short)c8[j]);
                            float dv = bfbits2f((unsigned short)d8[j]);
                            s0 = w00*av + w01*bv + w10*cv + w11*dv;
                        }
                        {
                            int j = jp*2 + 1;
                            float av = bfbits2f((unsigned short)a8[j]);
                            float bv = bfbits2f((unsigned short)b8[j]);
                            float cv = bfbits2f((unsigned short)c8[j]);
                            float dv = bfbits2f((unsigned short)d8[j]);
                            s1 = w00*av + w01*bv + w10*cv + w11*dv;
                        }
                        pk[g*4 + jp] = (unsigned int)f2bfbits(s0)
                                     | ((unsigned int)f2bfbits(s1) << 16);
                    }
                }
            }
        } else {
            int o00 = cy0*WW + cx0, o01 = cy0*WW + cx1;
            int o10 = cy1*WW + cx0, o11 = cy1*WW + cx1;
            float sv[20];
            #pragma unroll
            for (int c = 0; c < CIN2; c++) {
                const float* src;
                float sc = 1.f, sh = 0.f;
                if (L1) {
                    int part = (c < NHID) ? esrc[e] : edst[e];
                    int ch   = (c < NHID) ? c : c - NHID;
                    src = xp + ((size_t)(part*BB + b)*NHID + ch)*HWD;
                } else {
                    src = xin + (size_t)c*HWD;
                    sc = bnS[e*CIN2 + c]; sh = bnT[e*CIN2 + c];
                }
                float av = src[o00], bv = src[o01], cv = src[o10], dv = src[o11];
                if (!L1) {
                    av = fmaxf(fmaf(av, sc, sh), 0.f); bv = fmaxf(fmaf(bv, sc, sh), 0.f);
                    cv = fmaxf(fmaf(cv, sc, sh), 0.f); dv = fmaxf(fmaf(dv, sc, sh), 0.f);
                }
                sv[c] = w00*av + w01*bv + w10*cv + w11*dv;
            }
            #pragma unroll
            for (int jp = 0; jp < 10; jp++)
                pk[jp] = (unsigned int)f2bfbits(sv[2*jp])
                       | ((unsigned int)f2bfbits(sv[2*jp+1]) << 16);
        }

        {   // write own s-row (wave-private)
            unsigned short* mr = &stile[(size_t)tid*SROW];
            *reinterpret_cast<uint4*>(mr)      = make_uint4(pk[0], pk[1], pk[2], pk[3]);
            *reinterpret_cast<uint4*>(mr + 8)  = make_uint4(pk[4], pk[5], pk[6], pk[7]);
            *reinterpret_cast<uint2*>(mr + 16) = make_uint2(pk[8], pk[9]);
        }
        wave_lds_fence();

        // MFMA: acc[pixel][o] += s[pixel][c] * Wd[c][o]  (reads wave-own rows)
        {
            const s16x8* wsp = reinterpret_cast<const s16x8*>(wsf + (size_t)k*NT*512);
            s16x8 wb0 = wsp[lane];
            s16x8 wb1{};
            if constexpr (NT == 2) wb1 = wsp[64 + lane];
            #pragma unroll
            for (int mt = 0; mt < 4; mt++) {
                int pxl = wv*64 + mt*16 + lrow;
                s16x8 a = *reinterpret_cast<const s16x8*>(&stile[pxl*SROW + lkg*8]);
                sacc[mt][0] = __builtin_amdgcn_mfma_f32_16x16x32_bf16(a, wb0, sacc[mt][0], 0, 0, 0);
                if constexpr (NT == 2)
                    sacc[mt][1] = __builtin_amdgcn_mfma_f32_16x16x32_bf16(a, wb1, sacc[mt][1], 0, 0, 0);
            }
        }
        wave_lds_fence();   // A-reads drained before next tap's s-row write
    }

    // ---- per-wave BN partials (2-shuffle reduce, NON-atomic store) ----
    #pragma unroll
    for (int nt = 0; nt < NT; nt++) {
        int o = nt*16 + lrow;
        float ls = 0.f, lq = 0.f;
        #pragma unroll
        for (int mt = 0; mt < 4; mt++)
            #pragma unroll
            for (int r = 0; r < 4; r++) {
                float v = sacc[mt][nt][r];
                ls += v; lq += v*v;
            }
        ls += __shfl_xor(ls, 16); lq += __shfl_xor(lq, 16);
        ls += __shfl_xor(ls, 32); lq += __shfl_xor(lq, 32);
        if (lkg == 0 && o < COUT) {
            size_t pidx = (size_t)(flat*4 + wv)*COUT + o;
            pSum[pidx] = ls;
            pSq[pidx]  = lq;
        }
    }

    // ---- writeout: wave-quartered LDS bounce, then coalesced stores ----
    {
        float* ldsf = reinterpret_cast<float*>(stile) + wv*1280;  // 5120 B/wave
        #pragma unroll
        for (int mt = 0; mt < 4; mt++) {
            #pragma unroll
            for (int nt = 0; nt < NT; nt++) {
                int o = nt*16 + lrow;
                if (o < COUT) {
                    #pragma unroll
                    for (int r = 0; r < 4; r++) {
                        int lp = mt*16 + lkg*4 + r;          // 0..63 in-wave pixel
                        ldsf[o*64 + lp] = sacc[mt][nt][r];
                    }
                }
            }
        }
        wave_lds_fence();
        float* op = out + (size_t)(e*BB + b)*COUT*HWD + h*WW + w;
        #pragma unroll
        for (int o = 0; o < COUT; o++)
            op[(size_t)o*HWD] = ldsf[o*64 + (tid & 63)];
    }
}

// ---------------------------------------------------------------------------
// Fused msg + gate + q (scalar, MLP via 8-batched loads).  grid: (36, B, P)
// ---------------------------------------------------------------------------
__global__ __launch_bounds__(256)
void mgq_kernel(const float* __restrict__ t2all, const float* __restrict__ s2,
                const float* __restrict__ sh2, const float* __restrict__ o_w,
                const float* __restrict__ o_b, const float* __restrict__ a_w,
                const float* __restrict__ a_b, const float* __restrict__ xp,
                const float* __restrict__ xh,
                const float* __restrict__ att_w, const float* __restrict__ att_b,
                const float* __restrict__ du_w, const float* __restrict__ du_b,
                const float* __restrict__ dl_w, const float* __restrict__ dl_b,
                const int* __restrict__ esrc, const int* __restrict__ edst,
                const float* __restrict__ p_fea, const float* __restrict__ wq_all,
                float* __restrict__ y)
{
    int px = blockIdx.x * 256 + threadIdx.x;
    int b = blockIdx.y, p = blockIdx.z;

    float s = att_b[p];
    #pragma unroll
    for (int c = 0; c < NHID; c++)
        s += xp[((size_t)(p*BB + b)*NHID + c)*HWD + px] * att_w[p*NHID + c];
    float satt = sigf(s);

    int hs = (p < 4) ? 0 : 1;
    const float* dw = (p < 4) ? du_w : dl_w;
    float d = (p < 4) ? du_b[0] : dl_b[0];
    #pragma unroll
    for (int c = 0; c < NHID; c++)
        d += xh[((size_t)(hs*BB + b)*NHID + c)*HWD + px] * dw[c];
    float dec = sigf(d);

    float xpp = 0.f;
    for (int e = 0; e < NE; e++) {
        if (edst[e] != p) continue;
        float sab = o_b[e];
        #pragma unroll
        for (int c = 0; c < NHID; c++) {
            float v = t2all[((size_t)(e*BB + b)*NHID + c)*HWD + px];
            v = fmaxf(fmaf(v, s2[e*NHID+c], sh2[e*NHID+c]), 0.f);
            sab += v * o_w[e*NHID + c];
        }
        int sp = esrc[e];
        float sa = a_b[e];
        #pragma unroll
        for (int c = 0; c < NHID; c++)
            sa += xp[((size_t)(sp*BB + b)*NHID + c)*HWD + px] * a_w[e*NHID + c];
        xpp += sigf(sab) * (1.f - sigf(sa));
    }
    float gate = 1.f + dec + satt + xpp;

    const float* wq = wq_all + (size_t)p*NIN*NHID;
    const float* pf = p_fea + (size_t)b*NIN*HWD + px;
    float acc[NHID];
    #pragma unroll
    for (int o = 0; o < NHID; o++) acc[o] = 0.f;
    for (int c = 0; c < NIN; c += 8) {
        float v0 = pf[(size_t)(c+0)*HWD];
        float v1 = pf[(size_t)(c+1)*HWD];
        float v2 = pf[(size_t)(c+2)*HWD];
        float v3 = pf[(size_t)(c+3)*HWD];
        float v4 = pf[(size_t)(c+4)*HWD];
        float v5 = pf[(size_t)(c+5)*HWD];
        float v6 = pf[(size_t)(c+6)*HWD];
        float v7 = pf[(size_t)(c+7)*HWD];
        const float* wc = wq + c*NHID;
        #pragma unroll
        for (int o = 0; o < NHID; o++) acc[o] = fmaf(v0, wc[o], acc[o]);
        #pragma unroll
        for (int o = 0; o < NHID; o++) acc[o] = fmaf(v1, wc[NHID + o], acc[o]);
        #pragma unroll
        for (int o = 0; o < NHID; o++) acc[o] = fmaf(v2, wc[2*NHID + o], acc[o]);
        #pragma unroll
        for (int o = 0; o < NHID; o++) acc[o] = fmaf(v3, wc[3*NHID + o], acc[o]);
        #pragma unroll
        for (int o = 0; o < NHID; o++) acc[o] = fmaf(v4, wc[4*NHID + o], acc[o]);
        #pragma unroll
        for (int o = 0; o < NHID; o++) acc[o] = fmaf(v5, wc[5*NHID + o], acc[o]);
        #pragma unroll
        for (int o = 0; o < NHID; o++) acc[o] = fmaf(v6, wc[6*NHID + o], acc[o]);
        #pragma unroll
        for (int o = 0; o < NHID; o++) acc[o] = fmaf(v7, wc[7*NHID + o], acc[o]);
    }
    float* yp = y + ((size_t)(p*BB + b)*NHID)*HWD + px;
    #pragma unroll
    for (int o = 0; o < NHID; o++) yp[(size_t)o*HWD] = acc[o] * gate;
}

// ---------------------------------------------------------------------------
// out = relu(bn5(y));   grid: (36, B*HID, P)
// ---------------------------------------------------------------------------
__global__ __launch_bounds__(256)
void out_kernel(const float* __restrict__ y, const float* __restrict__ s5,
                const float* __restrict__ t5, float* __restrict__ out)
{
    int px = blockIdx.x * 256 + threadIdx.x;
    int bo = blockIdx.y, p = blockIdx.z;
    int b = bo / NHID, o = bo % NHID;
    size_t idx = ((size_t)(p*BB + b)*NHID + o)*HWD + px;
    out[idx] = fmaxf(fmaf(y[idx], s5[p*NHID+o], t5[p*NHID+o]), 0.f);
}

// ---------------------------------------------------------------------------
// launcher
// ---------------------------------------------------------------------------
extern "C" void kernel_launch(void* const* d_in, const int* in_sizes, int n_in,
                              void* d_out, int out_size, void* d_ws, size_t ws_size,
                              hipStream_t stream)
{
    (void)in_sizes; (void)n_in; (void)out_size; (void)ws_size;

    const float* p_fea  = (const float*)d_in[0];
    const float* xp     = (const float*)d_in[1];
    const float* xh     = (const float*)d_in[2];
    const float* att_w  = (const float*)d_in[3];
    const float* att_b  = (const float*)d_in[4];
    const float* du_w   = (const float*)d_in[5];
    const float* du_b   = (const float*)d_in[6];
    const float* dl_w   = (const float*)d_in[7];
    const float* dl_b   = (const float*)d_in[8];
    const float* upd_w  = (const float*)d_in[9];
    const float* upd_g  = (const float*)d_in[10];
    const float* upd_b  = (const float*)d_in[11];
    const float* off1_w = (const float*)d_in[12];
    const float* off1_b = (const float*)d_in[13];
    const float* dcn1_w = (const float*)d_in[14];
    const float* bn1_g  = (const float*)d_in[15];
    const float* bn1_b  = (const float*)d_in[16];
    const float* off2_w = (const float*)d_in[17];
    const float* off2_b = (const float*)d_in[18];
    const float* dcn2_w = (const float*)d_in[19];
    const float* bn2_g  = (const float*)d_in[20];
    const float* bn2_b  = (const float*)d_in[21];
    const float* out_w  = (const float*)d_in[22];
    const float* out_b  = (const float*)d_in[23];
    const float* aatt_w = (const float*)d_in[24];
    const float* aatt_b = (const float*)d_in[25];
    const int* esrc     = (const int*)d_in[26];
    const int* edst     = (const int*)d_in[27];
    float* outp = (float*)d_out;
    float* ws = (float*)d_ws;

    // workspace layout (float offsets; ushort arrays occupy half-floats)
    constexpr size_t o_x1   = 0;                                    // [E][B][20][HWD]
    constexpr size_t o_t2   = o_x1  + (size_t)NE*BB*CIN2*HWD;       // [E][B][10][HWD]
    constexpr size_t o_bf1  = o_t2  + (size_t)NE*BB*NHID*HWD;       // 110592 ush
    constexpr size_t o_b1   = o_bf1 + 55296;
    constexpr size_t o_ws1  = o_b1  + 324;                          // 110592 ush
    constexpr size_t o_bf2  = o_ws1 + 55296;                        // 110592 ush
    constexpr size_t o_b2   = o_bf2 + 55296;
    constexpr size_t o_ws2  = o_b2  + 324;                          // 55296 ush
    constexpr size_t o_uw   = o_ws2 + 27648;
    constexpr size_t o_bn1s = o_uw  + 15360;
    constexpr size_t o_bn1t = o_bn1s + NE*CIN2;
    constexpr size_t o_bn2s = o_bn1t + NE*CIN2;
    constexpr size_t o_bn2t = o_bn2s + NE*NHID;
    constexpr size_t o_bn5s = o_bn2t + NE*NHID;
    constexpr size_t o_bn5t = o_bn5s + NPART*NHID;
    // per-wave BN partials (fully overwritten each call; no zeroing needed)
    constexpr size_t o_p1u  = o_bn5t + NPART*NHID;   // [3456][20]
    constexpr size_t o_p1q  = o_p1u + 3456*20;
    constexpr size_t o_p2u  = o_p1q + 3456*20;       // [3456][10]
    constexpr size_t o_p2q  = o_p2u + 3456*10;
    constexpr size_t o_y    = o_p2q + 3456*10;                      // [P][B][10][HWD]
    float* x1 = ws + o_x1;
    float* t2 = ws + o_t2;
    float* y  = ws + o_y;
    unsigned short* bf1 = (unsigned short*)(ws + o_bf1);
    unsigned short* ws1 = (unsigned short*)(ws + o_ws1);
    unsigned short* bf2 = (unsigned short*)(ws + o_bf2);
    unsigned short* ws2 = (unsigned short*)(ws + o_ws2);

    // items: 403080 -> 1575 blocks
    xpose_weights<<<dim3(1575), 256, 0, stream>>>(
        off1_w, off1_b, dcn1_w, off2_w, off2_b, dcn2_w, upd_w,
        bf1, ws+o_b1, ws1, bf2, ws+o_b2, ws2, ws+o_uw);

    dcn_tiled<CIN2, true><<<dim3(36, BB, NE), 256, 0, stream>>>(
        nullptr, xp, esrc, edst, bf1, ws+o_b1, ws1,
        nullptr, nullptr, x1, ws+o_p1u, ws+o_p1q);

    bn_reduce<CIN2><<<dim3(NE*CIN2), 256, 0, stream>>>(
        ws+o_p1u, ws+o_p1q, bn1_g, bn1_b, ws+o_bn1s, ws+o_bn1t);

    dcn_tiled<NHID, false><<<dim3(36, BB, NE), 256, 0, stream>>>(
        x1, nullptr, esrc, edst, bf2, ws+o_b2, ws2,
        ws+o_bn1s, ws+o_bn1t, t2, ws+o_p2u, ws+o_p2q);

    bn_reduce<NHID><<<dim3(NE*NHID), 256, 0, stream>>>(
        ws+o_p2u, ws+o_p2q, bn2_g, bn2_b, ws+o_bn2s, ws+o_bn2t);

    mgq_kernel<<<dim3(36, BB, NPART), 256, 0, stream>>>(
        t2, ws+o_bn2s, ws+o_bn2t, out_w, out_b, aatt_w, aatt_b, xp, xh,
        att_w, att_b, du_w, du_b, dl_w, dl_b, esrc, edst,
        p_fea, ws+o_uw, y);

    bn_stats_flat<NHID><<<dim3(NPART*NHID), 256, 0, stream>>>(
        y, upd_g, upd_b, ws+o_bn5s, ws+o_bn5t);

    out_kernel<<<dim3(36, BB*NHID, NPART), 256, 0, stream>>>(
        y, ws+o_bn5s, ws+o_bn5t, outp);
}